// Round 11
// baseline (488.349 us; speedup 1.0000x reference)
//
#include <hip/hip_runtime.h>
#include <math.h>

#define N_ROWS 262144
#define K_COMP 256
#define D_DIM  128
#define WROWS 32        // rows per wave
#define KIN 256         // GEMM inner dim = concat(x^2 | x)

typedef _Float16 half8v __attribute__((ext_vector_type(8)));
typedef float    f32x4  __attribute__((ext_vector_type(4)));

static __device__ __constant__ float kLOG2PI = 1.8378770664093453f;

// ---------------- prep ----------------
// B = [iv | m2] (K_COMP x KIN) as fp16 hi/lo, FRAGMENT-LINEAR:
// (comp k, kin) -> lin = ((c*8+s)*64 + l)*8 + j,
//   c=k>>4, s=kin>>5, l=((kin>>3)&3)*16 + (k&15), j=kin&7.
__global__ __launch_bounds__(128) void gmm_prep(
    const float* __restrict__ means, const float* __restrict__ log_stds,
    const float* __restrict__ weights,
    _Float16* __restrict__ Bhi, _Float16* __restrict__ Blo,
    float* __restrict__ sigma, float* __restrict__ ck, double* __restrict__ wsq)
{
    int k = blockIdx.x;     // 0..255
    int d = threadIdx.x;    // 0..127
    float ls = log_stds[k * D_DIM + d];
    float mu = means[k * D_DIM + d];
    float iv = expf(-2.0f * ls);
    float m2 = -2.0f * mu * iv;
    sigma[k * D_DIM + d] = expf(ls);

    {
        int c = k >> 4;
        #pragma unroll
        for (int t = 0; t < 2; ++t) {
            int kin = t * 128 + d;
            float val = t ? m2 : iv;
            int s = kin >> 5;
            int l = ((kin >> 3) & 3) * 16 + (k & 15);
            int j = kin & 7;
            int lin = ((c * 8 + s) * 64 + l) * 8 + j;
            _Float16 hi = (_Float16)val;
            Bhi[lin] = hi;
            Blo[lin] = (_Float16)(val - (float)hi);
        }
    }

    float c = mu * mu * iv;
    float s = ls;
    float w1 = weights[d], w2 = weights[d + 128];
    float wm = fmaxf(w1, w2);

    __shared__ float red[8];
    int lane = d & 63, wv = d >> 6;
    #pragma unroll
    for (int o = 32; o > 0; o >>= 1) {
        c += __shfl_down(c, o, 64);
        s += __shfl_down(s, o, 64);
        wm = fmaxf(wm, __shfl_down(wm, o, 64));
    }
    if (lane == 0) { red[wv] = c; red[2 + wv] = s; red[4 + wv] = wm; }
    __syncthreads();
    float csum = red[0] + red[1];
    float ssum = red[2] + red[3];
    float wmax = fmaxf(red[4], red[5]);
    float we = expf(w1 - wmax) + expf(w2 - wmax);
    #pragma unroll
    for (int o = 32; o > 0; o >>= 1) we += __shfl_down(we, o, 64);
    if (lane == 0) red[6 + wv] = we;
    __syncthreads();
    if (d == 0) {
        float wsum = red[6] + red[7];
        float lw = weights[k] - (wmax + logf(wsum));   // log_softmax(weights)[k]
        ck[k] = -0.5f * (csum + (float)D_DIM * kLOG2PI) - ssum + lw;
        if (k == 0) *wsq = 0.0;
    }
}

// ---------------- main: barrier-free wave-owned MFMA GEMM ----------------
// R11: structural rewrite. R9/R10 falsified occupancy and intra-block
// pipelining; the stall is the lockstep block structure itself (4 barriers,
// LDS staging round-trip, cross-wave merge serializing 12 waves).
// New shape: each WAVE owns 32 rows x ALL 256 cols (acc[2][16], 128 regs).
//  - A-frags built straight from global x (16 rows x 128B per load group;
//    x-pass re-reads the x^2-pass's 16KB -> L2-hot). NO LDS, NO barriers.
//  - epilogue fully in-wave (16-lane shuffles); resample wave-local.
//  - B traffic unchanged vs R6 (8192 waves x 128KB = 1GB L2).
// 2 waves/SIMD (reg-bound) but waves fully independent; 96-MFMA k-step body
// (~1900cy) covers prefetched A/B latency. Manual next-s A prefetch.
// Spill tripwire: WRITE_SIZE > 150e3 KB -> revert to R6.
__global__ __launch_bounds__(256, 2) void gmm_main(
    const float* __restrict__ x, const float* __restrict__ noise,
    const float* __restrict__ means, const float* __restrict__ sigma,
    const _Float16* __restrict__ Bhi, const _Float16* __restrict__ Blo,
    const float* __restrict__ ck,
    float* __restrict__ out_x, float* __restrict__ out_idx, double* __restrict__ wsq)
{
    const int tid = threadIdx.x;
    const int wv  = tid >> 6;      // wave 0..3 (independent; no __syncthreads in kernel)
    const int l   = tid & 63;
    const int lm  = l & 15;        // col-in-frag / row-in-frag owner
    const int lh  = l >> 4;        // k-sub-slice
    const long n0 = ((long)blockIdx.x * 4 + wv) * WROWS;

    const float* xw = x + (size_t)n0 * D_DIM;
    const half8v* Bh = (const half8v*)Bhi;
    const half8v* Bl = (const half8v*)Blo;

    f32x4 acc[2][16];
    #pragma unroll
    for (int rf = 0; rf < 2; ++rf)
        #pragma unroll
        for (int cf = 0; cf < 16; ++cf)
            acc[rf][cf] = (f32x4){0.0f, 0.0f, 0.0f, 0.0f};

    // A-load helper: row-frag rf, k-col-offset d0 (+ lane's lh*8), 8 floats
#define ALOAD(dst0, dst1, rf, d0) \
    dst0 = *(const float4*)&xw[((rf) * 16 + lm) * D_DIM + (d0) + lh * 8]; \
    dst1 = *(const float4*)&xw[((rf) * 16 + lm) * D_DIM + (d0) + lh * 8 + 4];

    // build fp16 hi/lo frags from 2 float4 (optionally squared)
#define ACVT(ah_, al_, a0, a1, SQ) { \
    float xe[8] = {a0.x, a0.y, a0.z, a0.w, a1.x, a1.y, a1.z, a1.w}; \
    _Pragma("unroll") \
    for (int j = 0; j < 8; ++j) { \
        float v = (SQ) ? xe[j] * xe[j] : xe[j]; \
        _Float16 h = (_Float16)v; \
        ah_[j] = h; al_[j] = (_Float16)(v - (float)h); } }

    // one k-half: 4 s-steps, global s = ss + SBIAS, A col offset = ss*32
#define KHALF(SQ, SBIAS) { \
    float4 c00, c01, c10, c11, p00, p01, p10, p11; \
    ALOAD(c00, c01, 0, 0) ALOAD(c10, c11, 1, 0) \
    _Pragma("unroll 1") \
    for (int ss = 0; ss < 4; ++ss) { \
        if (ss < 3) { ALOAD(p00, p01, 0, (ss + 1) * 32) ALOAD(p10, p11, 1, (ss + 1) * 32) } \
        half8v ah[2], al[2]; \
        ACVT(ah[0], al[0], c00, c01, SQ) \
        ACVT(ah[1], al[1], c10, c11, SQ) \
        int s = ss + (SBIAS); \
        _Pragma("unroll") \
        for (int cf = 0; cf < 16; ++cf) { \
            int bidx = (cf * 8 + s) * 64 + l; \
            half8v bh = Bh[bidx], bl = Bl[bidx]; \
            _Pragma("unroll") \
            for (int rf = 0; rf < 2; ++rf) { \
                acc[rf][cf] = __builtin_amdgcn_mfma_f32_16x16x32_f16(ah[rf], bh, acc[rf][cf], 0, 0, 0); \
                acc[rf][cf] = __builtin_amdgcn_mfma_f32_16x16x32_f16(ah[rf], bl, acc[rf][cf], 0, 0, 0); \
                acc[rf][cf] = __builtin_amdgcn_mfma_f32_16x16x32_f16(al[rf], bh, acc[rf][cf], 0, 0, 0); \
            } \
        } \
        c00 = p00; c01 = p01; c10 = p10; c11 = p11; \
    } }

    KHALF(1, 0)   // x^2 * iv   (kin 0..127)
    KHALF(0, 4)   // x  * m2    (kin 128..255)

    // ---- epilogue: fully in-wave softmax/argmax/Q ----
    // C/D layout (verified m89): col = lane&15, row = (lane>>4)*4 + reg.
    float ckv[16];
    #pragma unroll
    for (int cf = 0; cf < 16; ++cf) ckv[cf] = ck[cf * 16 + lm];

    int amreg[2][4];
    float qacc = 0.0f;
    #pragma unroll
    for (int rf = 0; rf < 2; ++rf) {
        #pragma unroll
        for (int reg = 0; reg < 4; ++reg) {
            float jv[16];
            float m = -INFINITY; int am = 0;
            #pragma unroll
            for (int cf = 0; cf < 16; ++cf) {
                float v = fmaf(-0.5f, acc[rf][cf][reg], ckv[cf]);
                jv[cf] = v;
                int col = cf * 16 + lm;
                if (v > m) { m = v; am = col; }   // cf ascending => first-max kept
            }
            #pragma unroll
            for (int o = 1; o < 16; o <<= 1) {
                float om = __shfl_xor(m, o, 16);
                int   oa = __shfl_xor(am, o, 16);
                if (om > m || (om == m && oa < am)) { m = om; am = oa; }
            }
            float es = 0.0f, qs = 0.0f;
            #pragma unroll
            for (int cf = 0; cf < 16; ++cf) {
                float e = __expf(jv[cf] - m);
                es += e; qs = fmaf(e, jv[cf], qs);
            }
            #pragma unroll
            for (int o = 1; o < 16; o <<= 1) {
                es += __shfl_xor(es, o, 16);
                qs += __shfl_xor(qs, o, 16);
            }
            if (lm == 0) qacc += __fdividef(qs, es);
            amreg[rf][reg] = am;
        }
    }
    // wave Q reduce (qacc nonzero on lm==0 lanes), one atomic per wave
    #pragma unroll
    for (int o = 1; o < 64; o <<= 1) qacc += __shfl_xor(qacc, o, 64);

    // ---- resample: wave-local, fully unrolled (static amreg indexing) ----
    int idxmine = 0;
    #pragma unroll
    for (int r = 0; r < WROWS; ++r) {
        const int rf = r >> 4, lhr = (r >> 2) & 3, reg = r & 3;
        const int idx = __shfl(amreg[rf][reg], lhr * 16, 64);
        if (l == r) idxmine = idx;
        const long n = n0 + r;
        float2 mv = *(const float2*)&means[idx * D_DIM + l * 2];
        float2 sv = *(const float2*)&sigma[idx * D_DIM + l * 2];
        float2 nv = *(const float2*)&noise[n * D_DIM + l * 2];
        float2 ov;
        ov.x = mv.x + sv.x * nv.x * 0.1f;
        ov.y = mv.y + sv.y * nv.y * 0.1f;
        *(float2*)&out_x[n * D_DIM + l * 2] = ov;
    }
    if (l < WROWS) out_idx[n0 + l] = (float)idxmine;
    if (l == 0) atomicAdd(wsq, (double)qacc);

#undef ALOAD
#undef ACVT
#undef KHALF
}

__global__ void gmm_finalize(const double* __restrict__ wsq, float* __restrict__ out_q)
{
    *out_q = (float)(*wsq * (1.0 / ((double)N_ROWS * (double)K_COMP)));
}

extern "C" void kernel_launch(void* const* d_in, const int* in_sizes, int n_in,
                              void* d_out, int out_size, void* d_ws, size_t ws_size,
                              hipStream_t stream)
{
    const float* x        = (const float*)d_in[0];
    const float* means    = (const float*)d_in[1];
    const float* log_stds = (const float*)d_in[2];
    const float* weights  = (const float*)d_in[3];
    const float* noise    = (const float*)d_in[4];

    float* out_x   = (float*)d_out;                          // [N, D]
    float* out_idx = (float*)d_out + (size_t)N_ROWS * D_DIM; // [N]
    float* out_q   = out_idx + N_ROWS;                       // scalar

    // ws layout (floats): Bhi[32768 f] | Blo[32768 f] | sigma[32768] | ck[256] | (double) wsq
    float*     ws    = (float*)d_ws;
    _Float16*  Bhi   = (_Float16*)ws;
    _Float16*  Blo   = (_Float16*)(ws + 32768);
    float*     sigma = ws + 65536;
    float*     ckp   = ws + 98304;
    double*    wsq   = (double*)(ws + 98560);

    hipLaunchKernelGGL(gmm_prep, dim3(K_COMP), dim3(D_DIM), 0, stream,
                       means, log_stds, weights, Bhi, Blo, sigma, ckp, wsq);
    hipLaunchKernelGGL(gmm_main, dim3(N_ROWS / (WROWS * 4)), dim3(256), 0, stream,
                       x, noise, means, sigma, Bhi, Blo, ckp, out_x, out_idx, wsq);
    hipLaunchKernelGGL(gmm_finalize, dim3(1), dim3(1), 0, stream, wsq, out_q);
}

// Round 12
// 409.142 us; speedup vs baseline: 1.1936x; 1.1936x over previous
//
#include <hip/hip_runtime.h>
#include <math.h>

#define N_ROWS 262144
#define K_COMP 256
#define D_DIM  128
#define BN 32           // rows per block (R12: halved vs R6 to double blocks/CU)
#define KIN 256         // GEMM inner dim = concat(x^2 | x)

typedef _Float16 half8v __attribute__((ext_vector_type(8)));
typedef _Float16 half4v __attribute__((ext_vector_type(4)));
typedef float    f32x4  __attribute__((ext_vector_type(4)));

static __device__ __constant__ float kLOG2PI = 1.8378770664093453f;

// ---------------- prep ----------------
// B = [iv | m2] (K_COMP x KIN) as fp16 hi/lo, FRAGMENT-LINEAR:
// (comp k, kin) -> lin = ((c*8+s)*64 + l)*8 + j,
//   c=k>>4, s=kin>>5, l=((kin>>3)&3)*16 + (k&15), j=kin&7.
__global__ __launch_bounds__(128) void gmm_prep(
    const float* __restrict__ means, const float* __restrict__ log_stds,
    const float* __restrict__ weights,
    _Float16* __restrict__ Bhi, _Float16* __restrict__ Blo,
    float* __restrict__ sigma, float* __restrict__ ck, double* __restrict__ wsq)
{
    int k = blockIdx.x;     // 0..255
    int d = threadIdx.x;    // 0..127
    float ls = log_stds[k * D_DIM + d];
    float mu = means[k * D_DIM + d];
    float iv = expf(-2.0f * ls);
    float m2 = -2.0f * mu * iv;
    sigma[k * D_DIM + d] = expf(ls);

    {
        int c = k >> 4;
        #pragma unroll
        for (int t = 0; t < 2; ++t) {
            int kin = t * 128 + d;
            float val = t ? m2 : iv;
            int s = kin >> 5;
            int l = ((kin >> 3) & 3) * 16 + (k & 15);
            int j = kin & 7;
            int lin = ((c * 8 + s) * 64 + l) * 8 + j;
            _Float16 hi = (_Float16)val;
            Bhi[lin] = hi;
            Blo[lin] = (_Float16)(val - (float)hi);
        }
    }

    float c = mu * mu * iv;
    float s = ls;
    float w1 = weights[d], w2 = weights[d + 128];
    float wm = fmaxf(w1, w2);

    __shared__ float red[8];
    int lane = d & 63, wv = d >> 6;
    #pragma unroll
    for (int o = 32; o > 0; o >>= 1) {
        c += __shfl_down(c, o, 64);
        s += __shfl_down(s, o, 64);
        wm = fmaxf(wm, __shfl_down(wm, o, 64));
    }
    if (lane == 0) { red[wv] = c; red[2 + wv] = s; red[4 + wv] = wm; }
    __syncthreads();
    float csum = red[0] + red[1];
    float ssum = red[2] + red[3];
    float wmax = fmaxf(red[4], red[5]);
    float we = expf(w1 - wmax) + expf(w2 - wmax);
    #pragma unroll
    for (int o = 32; o > 0; o >>= 1) we += __shfl_down(we, o, 64);
    if (lane == 0) red[6 + wv] = we;
    __syncthreads();
    if (d == 0) {
        float wsum = red[6] + red[7];
        float lw = weights[k] - (wmax + logf(wsum));   // log_softmax(weights)[k]
        ck[k] = -0.5f * (csum + (float)D_DIM * kLOG2PI) - ssum + lw;
        if (k == 0) *wsq = 0.0;
    }
}

// ---------------- main: MFMA quad GEMM + softmax/argmax + resample ----------------
// R12 vs R6 (champion 224us): ONE knob -- BN 64->32. Same 4-wave/64-col-per-wave
// geometry, same swizzle, same staging/epilogue structure. acc/thread 64->32 f32,
// total reg demand ~148->~100, so __launch_bounds__(256,4) (cap 128) gives
// 4 blocks/CU = 16 waves/CU WITHOUT spill (R7/R8 failure) and WITHOUT R9's
// duplicated A-reads/bank conflicts (per-wave access pattern unchanged).
// Cost: B L2 traffic 1->2GB (~60us aggregate at 34.5TB/s, far under BW).
// Tripwire: WRITE_SIZE > 150e3 KB -> spill -> revert to R6.
// Pre-commit: occ>=45% + dur>=210 => wave-count can't hide this latency family.
__global__ __launch_bounds__(256, 4) void gmm_main(
    const float* __restrict__ x, const float* __restrict__ noise,
    const float* __restrict__ means, const float* __restrict__ sigma,
    const _Float16* __restrict__ Bhi, const _Float16* __restrict__ Blo,
    const float* __restrict__ ck,
    float* __restrict__ out_x, float* __restrict__ out_idx, double* __restrict__ wsq)
{
    __shared__ char  sA[2][BN * 256];      // [hi|lo][row][128 halves], swizzled; reused per k-half
    __shared__ float sCk[K_COMP];
    __shared__ float sMax[BN][4];
    __shared__ int   sAm [BN][4];
    __shared__ float sEs [BN][4];
    __shared__ float sQs [BN][4];
    __shared__ int   sIdx[BN];

    const int tid = threadIdx.x;
    const int w   = tid >> 6;      // wave 0..3
    const int l   = tid & 63;      // lane
    const int lm  = l & 15;
    const int lh  = l >> 4;
    const long n0 = (long)blockIdx.x * BN;

    sCk[tid] = ck[tid];

    const float4* xg = (const float4*)(x + (size_t)n0 * D_DIM);

    // ---- stage phase A: x^2 hi/lo planes (1024 float4 / 256 thr = 4 iters) ----
    #pragma unroll
    for (int it = 0; it < 4; ++it) {
        int g = it * 256 + tid;
        int row = g >> 5, d4 = g & 31;         // d = d4*4
        float4 xv = xg[g];
        float xe[4] = {xv.x, xv.y, xv.z, xv.w};
        half4v h, lo;
        #pragma unroll
        for (int cc = 0; cc < 4; ++cc) {
            float vv = xe[cc] * xe[cc];
            _Float16 a = (_Float16)vv;
            h[cc] = a; lo[cc] = (_Float16)(vv - (float)a);
        }
        unsigned off = ((unsigned)(row * 256 + d4 * 8)) ^ ((unsigned)(row & 7) << 4);
        *(half4v*)(sA[0] + off) = h;
        *(half4v*)(sA[1] + off) = lo;
    }
    __syncthreads();

    f32x4 acc[2][4];
    #pragma unroll
    for (int rf = 0; rf < 2; ++rf)
        #pragma unroll
        for (int cf = 0; cf < 4; ++cf)
            acc[rf][cf] = (f32x4){0.0f, 0.0f, 0.0f, 0.0f};

    const half8v* Bh = (const half8v*)Bhi;
    const half8v* Bl = (const half8v*)Blo;

    // ---- k-half 1: s = 0..3 (x^2 * iv terms) ----
    #pragma unroll 2
    for (int s = 0; s < 4; ++s) {
        half8v ah[2], al[2], bh4[4], bl4[4];
        #pragma unroll
        for (int rf = 0; rf < 2; ++rf) {
            int row = rf * 16 + lm;
            unsigned off = ((unsigned)(row * 256 + s * 64 + lh * 16))
                         ^ ((unsigned)(row & 7) << 4);
            ah[rf] = *(const half8v*)(sA[0] + off);
            al[rf] = *(const half8v*)(sA[1] + off);
        }
        #pragma unroll
        for (int cf = 0; cf < 4; ++cf) {
            int bidx = ((w * 4 + cf) * 8 + s) * 64 + l;
            bh4[cf] = Bh[bidx];
            bl4[cf] = Bl[bidx];
        }
        #pragma unroll
        for (int rf = 0; rf < 2; ++rf)
            #pragma unroll
            for (int cf = 0; cf < 4; ++cf) {
                acc[rf][cf] = __builtin_amdgcn_mfma_f32_16x16x32_f16(ah[rf], bh4[cf], acc[rf][cf], 0, 0, 0);
                acc[rf][cf] = __builtin_amdgcn_mfma_f32_16x16x32_f16(ah[rf], bl4[cf], acc[rf][cf], 0, 0, 0);
                acc[rf][cf] = __builtin_amdgcn_mfma_f32_16x16x32_f16(al[rf], bh4[cf], acc[rf][cf], 0, 0, 0);
            }
    }

    // re-read x tile (L2-warm) for phase B; issue before the barrier so the
    // vmcnt wait overlaps the barrier wait.
    float4 xv2[4];
    #pragma unroll
    for (int it = 0; it < 4; ++it) xv2[it] = xg[it * 256 + tid];

    __syncthreads();   // readers of x^2 planes done

    // ---- stage phase B: x hi/lo planes (same buffer) ----
    #pragma unroll
    for (int it = 0; it < 4; ++it) {
        int g = it * 256 + tid;
        int row = g >> 5, d4 = g & 31;
        float xe[4] = {xv2[it].x, xv2[it].y, xv2[it].z, xv2[it].w};
        half4v h, lo;
        #pragma unroll
        for (int cc = 0; cc < 4; ++cc) {
            float v = xe[cc];
            _Float16 a = (_Float16)v;
            h[cc] = a; lo[cc] = (_Float16)(v - (float)a);
        }
        unsigned off = ((unsigned)(row * 256 + d4 * 8)) ^ ((unsigned)(row & 7) << 4);
        *(half4v*)(sA[0] + off) = h;
        *(half4v*)(sA[1] + off) = lo;
    }
    __syncthreads();

    // ---- k-half 2: s = 4..7 (x * m2 terms); A physical step = s-4 ----
    #pragma unroll 2
    for (int s = 4; s < 8; ++s) {
        half8v ah[2], al[2], bh4[4], bl4[4];
        #pragma unroll
        for (int rf = 0; rf < 2; ++rf) {
            int row = rf * 16 + lm;
            unsigned off = ((unsigned)(row * 256 + (s - 4) * 64 + lh * 16))
                         ^ ((unsigned)(row & 7) << 4);
            ah[rf] = *(const half8v*)(sA[0] + off);
            al[rf] = *(const half8v*)(sA[1] + off);
        }
        #pragma unroll
        for (int cf = 0; cf < 4; ++cf) {
            int bidx = ((w * 4 + cf) * 8 + s) * 64 + l;
            bh4[cf] = Bh[bidx];
            bl4[cf] = Bl[bidx];
        }
        #pragma unroll
        for (int rf = 0; rf < 2; ++rf)
            #pragma unroll
            for (int cf = 0; cf < 4; ++cf) {
                acc[rf][cf] = __builtin_amdgcn_mfma_f32_16x16x32_f16(ah[rf], bh4[cf], acc[rf][cf], 0, 0, 0);
                acc[rf][cf] = __builtin_amdgcn_mfma_f32_16x16x32_f16(ah[rf], bl4[cf], acc[rf][cf], 0, 0, 0);
                acc[rf][cf] = __builtin_amdgcn_mfma_f32_16x16x32_f16(al[rf], bh4[cf], acc[rf][cf], 0, 0, 0);
            }
    }

    // ---- epilogue 1: per-row softmax/argmax partials (per wave: 64 cols) ----
    // C/D layout (verified m89): col = lane&15, row = (lane>>4)*4 + reg.
    float ckv[4];
    #pragma unroll
    for (int cf = 0; cf < 4; ++cf) ckv[cf] = sCk[w * 64 + cf * 16 + lm];

    #pragma unroll
    for (int rf = 0; rf < 2; ++rf) {
        #pragma unroll
        for (int reg = 0; reg < 4; ++reg) {
            int row = rf * 16 + lh * 4 + reg;
            float jv[4];
            float m = -INFINITY; int am = 0;
            #pragma unroll
            for (int cf = 0; cf < 4; ++cf) {
                float v = fmaf(-0.5f, acc[rf][cf][reg], ckv[cf]);
                jv[cf] = v;
                int col = w * 64 + cf * 16 + lm;
                if (v > m) { m = v; am = col; }    // cf ascending => first-max kept
            }
            #pragma unroll
            for (int o = 1; o < 16; o <<= 1) {
                float om = __shfl_xor(m, o, 16);
                int   oa = __shfl_xor(am, o, 16);
                if (om > m || (om == m && oa < am)) { m = om; am = oa; }
            }
            float es = 0.0f, qs = 0.0f;
            #pragma unroll
            for (int cf = 0; cf < 4; ++cf) {
                float e = __expf(jv[cf] - m);
                es += e; qs = fmaf(e, jv[cf], qs);
            }
            #pragma unroll
            for (int o = 1; o < 16; o <<= 1) {
                es += __shfl_xor(es, o, 16);
                qs += __shfl_xor(qs, o, 16);
            }
            if (lm == 0) {
                sMax[row][w] = m; sAm[row][w] = am;
                sEs [row][w] = es; sQs[row][w] = qs;
            }
        }
    }

    // pre-issue noise loads (idx-independent): 8 rows per wave
    const int wv = tid >> 6, lane = tid & 63;
    float2 nvv[8];
    #pragma unroll
    for (int r8 = 0; r8 < 8; ++r8)
        nvv[r8] = *(const float2*)&noise[(n0 + wv * 8 + r8) * D_DIM + lane * 2];

    __syncthreads();

    // ---- epilogue 2: cross-wave online-softmax merge, one thread per row ----
    float qv = 0.0f;           // block Q sum, atomic deferred to the very end
    if (tid < BN) {
        const int row = tid;
        float m = sMax[row][0]; int am = sAm[row][0];
        float es = sEs[row][0], qs = sQs[row][0];
        #pragma unroll
        for (int w2 = 1; w2 < 4; ++w2) {
            float mw = sMax[row][w2];
            if (mw > m) {
                float f = __expf(m - mw);
                es = es * f + sEs[row][w2];
                qs = qs * f + sQs[row][w2];
                m = mw; am = sAm[row][w2];
            } else {
                float f = __expf(mw - m);
                es += sEs[row][w2] * f;
                qs += sQs[row][w2] * f;
            }
        }
        sIdx[row] = am;
        float q = __fdividef(qs, es);
        #pragma unroll
        for (int o = 1; o < 64; o <<= 1) q += __shfl_xor(q, o, 64);
        qv = q;
    }
    __syncthreads();

    // ---- epilogue 3: wave-contiguous resample writes (8 rows/wave) ----
    #pragma unroll
    for (int r8 = 0; r8 < 8; ++r8) {
        const int row = wv * 8 + r8;
        const int idx = sIdx[row];
        const long n = n0 + row;
        float2 mv = *(const float2*)&means[idx * D_DIM + lane * 2];
        float2 sv = *(const float2*)&sigma[idx * D_DIM + lane * 2];
        float2 ov;
        ov.x = mv.x + sv.x * nvv[r8].x * 0.1f;
        ov.y = mv.y + sv.y * nvv[r8].y * 0.1f;
        *(float2*)&out_x[n * D_DIM + lane * 2] = ov;
    }
    if (tid < BN) out_idx[n0 + tid] = (float)sIdx[tid];

    // contended device-scope atomic last: off every other path
    if (tid == 0) atomicAdd(wsq, (double)qv);
}

__global__ void gmm_finalize(const double* __restrict__ wsq, float* __restrict__ out_q)
{
    *out_q = (float)(*wsq * (1.0 / ((double)N_ROWS * (double)K_COMP)));
}

extern "C" void kernel_launch(void* const* d_in, const int* in_sizes, int n_in,
                              void* d_out, int out_size, void* d_ws, size_t ws_size,
                              hipStream_t stream)
{
    const float* x        = (const float*)d_in[0];
    const float* means    = (const float*)d_in[1];
    const float* log_stds = (const float*)d_in[2];
    const float* weights  = (const float*)d_in[3];
    const float* noise    = (const float*)d_in[4];

    float* out_x   = (float*)d_out;                          // [N, D]
    float* out_idx = (float*)d_out + (size_t)N_ROWS * D_DIM; // [N]
    float* out_q   = out_idx + N_ROWS;                       // scalar

    // ws layout (floats): Bhi[32768 f] | Blo[32768 f] | sigma[32768] | ck[256] | (double) wsq
    float*     ws    = (float*)d_ws;
    _Float16*  Bhi   = (_Float16*)ws;
    _Float16*  Blo   = (_Float16*)(ws + 32768);
    float*     sigma = ws + 65536;
    float*     ckp   = ws + 98304;
    double*    wsq   = (double*)(ws + 98560);

    hipLaunchKernelGGL(gmm_prep, dim3(K_COMP), dim3(D_DIM), 0, stream,
                       means, log_stds, weights, Bhi, Blo, sigma, ckp, wsq);
    hipLaunchKernelGGL(gmm_main, dim3(N_ROWS / BN), dim3(256), 0, stream,
                       x, noise, means, sigma, Bhi, Blo, ckp, out_x, out_idx, wsq);
    hipLaunchKernelGGL(gmm_finalize, dim3(1), dim3(1), 0, stream, wsq, out_q);
}